// Round 1
// baseline (1372.017 us; speedup 1.0000x reference)
//
#include <hip/hip_runtime.h>
#include <hip/hip_bf16.h>

#define IN_F 4096
#define OUT_F 11008
#define GSIZE 128
#define M_TOTAL 8192

typedef float f32x4 __attribute__((ext_vector_type(4)));
typedef unsigned short u16x8 __attribute__((ext_vector_type(8)));
typedef unsigned int u32x4 __attribute__((ext_vector_type(4)));
typedef __bf16 bf16x8 __attribute__((ext_vector_type(8)));
typedef float f32x4a __attribute__((ext_vector_type(4)));

__device__ __forceinline__ unsigned short f2bf(float f) {
    union { float f; unsigned int u; } v;
    v.f = f;
    unsigned int u = v.u;
    unsigned int r = (u + 0x7fffu + ((u >> 16) & 1u)) >> 16;
    return (unsigned short)r;
}

// ---------------------------------------------------------------------------
// Pass 1: dequantize packed int4 weights -> W^T bf16 [OUT_F][IN_F] in ws.
// grid: (OUT_F/256, IN_F/32), block 256.
// Each thread: one output column n, 32 consecutive k (16 packed int32 rows).
// Reads coalesced across lanes (consecutive n); writes 64 B contiguous/thread.
// ---------------------------------------------------------------------------
__global__ void dequant_w_kernel(const int* __restrict__ qw,
                                 const float* __restrict__ scales,
                                 const float* __restrict__ zeros,
                                 unsigned short* __restrict__ wt) {
    const int n  = blockIdx.x * 256 + threadIdx.x;   // 0..11007
    const int k0 = blockIdx.y * 32;                  // 0..4064, step 32
    const int g  = k0 >> 7;                          // group (32-chunk within one group)
    const float s = scales[(size_t)g * OUT_F + n];
    const float z = zeros[(size_t)g * OUT_F + n];

    unsigned short outv[32];
#pragma unroll
    for (int i = 0; i < 16; ++i) {
        int q = qw[(size_t)(k0 / 2 + i) * OUT_F + n];
        float lo = (float)((q & 15) - 8) * s + z;        // even k = low nibble
        float hi = (float)(((q >> 4) & 15) - 8) * s + z; // odd k  = high nibble
        outv[2 * i]     = f2bf(lo);
        outv[2 * i + 1] = f2bf(hi);
    }
    u16x8* dst = (u16x8*)(wt + (size_t)n * IN_F + k0);
    const u16x8* src = (const u16x8*)outv;
#pragma unroll
    for (int i = 0; i < 4; ++i) dst[i] = src[i];
}

// ---------------------------------------------------------------------------
// Pass 2: GEMM  out[M][N] = x[M][K] * W[K][N] + bias
// BM=BN=128, BK=64, 256 threads (4 waves, 2x2), 4x4 frags of 16x16x32 bf16.
// A staged from fp32 x (convert during staging); B staged from bf16 W^T
// (PREW=true) or dequantized on the fly from qweight (PREW=false fallback).
// LDS padded stride (BK+8) to avoid bank conflicts on fragment reads.
// ---------------------------------------------------------------------------
template <bool PREW>
__global__ __launch_bounds__(256, 2)
void gemm_kernel(const float* __restrict__ x,
                 const unsigned short* __restrict__ wt,
                 const int* __restrict__ qw,
                 const float* __restrict__ scales,
                 const float* __restrict__ zeros,
                 const float* __restrict__ bias,
                 float* __restrict__ out) {
    constexpr int BM = 128, BN = 128, BK = 64;
    constexpr int LDK = BK + 8;   // 72 elements, 144 B stride (16B-aligned)
    constexpr int NT = IN_F / BK; // 64 k-tiles

    __shared__ unsigned short As[BM * LDK];
    __shared__ unsigned short Bs[BN * LDK];

    const int bid = blockIdx.x;
    constexpr int NB_N = OUT_F / BN; // 86
    const int m0 = (bid / NB_N) * BM;
    const int n0 = (bid % NB_N) * BN;

    const int tid  = threadIdx.x;
    const int lane = tid & 63;
    const int wave = tid >> 6;
    const int wr = wave >> 1, wc = wave & 1;

    // staging geometry (both A and B): thread -> (row = tid>>3 + 32*pass, col = (tid&7)*8)
    const int st_row = tid >> 3;      // 0..31
    const int st_col = (tid & 7) * 8; // 0,8,..,56

    // prefetch registers
    f32x4 areg[4][2];
    u32x4 breg[4];            // PREW path: 8 bf16 per pass
    int   qreg[16];           // !PREW path
    float s_, z_;
    const int b_n  = tid & 127;        // !PREW: column within tile
    const int b_kp = (tid >> 7) * 16;  // !PREW: packed-row base (0 or 16)

    auto load_tile = [&](int kt) {
        {
            const float* base = x + (size_t)m0 * IN_F + (size_t)kt * BK + st_col;
#pragma unroll
            for (int p = 0; p < 4; ++p) {
                const float* rp = base + (size_t)(p * 32 + st_row) * IN_F;
                areg[p][0] = *(const f32x4*)rp;
                areg[p][1] = *(const f32x4*)(rp + 4);
            }
        }
        if constexpr (PREW) {
            const unsigned short* base = wt + (size_t)n0 * IN_F + (size_t)kt * BK + st_col;
#pragma unroll
            for (int p = 0; p < 4; ++p)
                breg[p] = *(const u32x4*)(base + (size_t)(p * 32 + st_row) * IN_F);
        } else {
            const int kp0 = kt * (BK / 2) + b_kp;
#pragma unroll
            for (int i = 0; i < 16; ++i)
                qreg[i] = qw[(size_t)(kp0 + i) * OUT_F + n0 + b_n];
            const int g = (kt * BK) >> 7;
            s_ = scales[(size_t)g * OUT_F + n0 + b_n];
            z_ = zeros[(size_t)g * OUT_F + n0 + b_n];
        }
    };

    auto write_lds = [&]() {
#pragma unroll
        for (int p = 0; p < 4; ++p) {
            u16x8 v;
#pragma unroll
            for (int e = 0; e < 4; ++e) {
                v[e]     = f2bf(areg[p][0][e]);
                v[e + 4] = f2bf(areg[p][1][e]);
            }
            *(u16x8*)(&As[(p * 32 + st_row) * LDK + st_col]) = v;
        }
        if constexpr (PREW) {
#pragma unroll
            for (int p = 0; p < 4; ++p)
                *(u32x4*)(&Bs[(p * 32 + st_row) * LDK + st_col]) = breg[p];
        } else {
            unsigned short tmp[32];
#pragma unroll
            for (int i = 0; i < 16; ++i) {
                int q = qreg[i];
                tmp[2 * i]     = f2bf((float)((q & 15) - 8) * s_ + z_);
                tmp[2 * i + 1] = f2bf((float)(((q >> 4) & 15) - 8) * s_ + z_);
            }
            const u16x8* srcv = (const u16x8*)tmp;
#pragma unroll
            for (int i = 0; i < 4; ++i)
                *(u16x8*)(&Bs[b_n * LDK + 2 * b_kp + 8 * i]) = srcv[i];
        }
    };

    f32x4a acc[4][4];
#pragma unroll
    for (int i = 0; i < 4; ++i)
#pragma unroll
        for (int j = 0; j < 4; ++j) acc[i][j] = (f32x4a)0.0f;

    load_tile(0);

#pragma unroll 1
    for (int kt = 0; kt < NT; ++kt) {
        __syncthreads();   // previous tile's compute done; LDS free
        write_lds();
        __syncthreads();   // tile visible
        if (kt + 1 < NT) load_tile(kt + 1);  // overlap next global loads with MFMA

#pragma unroll
        for (int kk = 0; kk < 2; ++kk) {
            const int kidx = kk * 32 + ((lane >> 4) << 3);
            bf16x8 af[4], bfv[4];
#pragma unroll
            for (int i = 0; i < 4; ++i)
                af[i] = *(const bf16x8*)(&As[(wr * 64 + i * 16 + (lane & 15)) * LDK + kidx]);
#pragma unroll
            for (int j = 0; j < 4; ++j)
                bfv[j] = *(const bf16x8*)(&Bs[(wc * 64 + j * 16 + (lane & 15)) * LDK + kidx]);
#pragma unroll
            for (int i = 0; i < 4; ++i)
#pragma unroll
                for (int j = 0; j < 4; ++j)
                    acc[i][j] = __builtin_amdgcn_mfma_f32_16x16x32_bf16(af[i], bfv[j], acc[i][j], 0, 0, 0);
        }
    }

    // epilogue: C/D layout col = lane&15, row = (lane>>4)*4 + q
    const int orow_base = m0 + wr * 64 + ((lane >> 4) << 2);
    const int ocol_base = n0 + wc * 64 + (lane & 15);
#pragma unroll
    for (int j = 0; j < 4; ++j) {
        const float bv = bias[ocol_base + j * 16];
#pragma unroll
        for (int i = 0; i < 4; ++i) {
#pragma unroll
            for (int q = 0; q < 4; ++q) {
                out[(size_t)(orow_base + i * 16 + q) * OUT_F + (ocol_base + j * 16)] =
                    acc[i][j][q] + bv;
            }
        }
    }
}

// ---------------------------------------------------------------------------
extern "C" void kernel_launch(void* const* d_in, const int* in_sizes, int n_in,
                              void* d_out, int out_size, void* d_ws, size_t ws_size,
                              hipStream_t stream) {
    const float* x      = (const float*)d_in[0];
    const int*   qw     = (const int*)d_in[1];
    const float* scales = (const float*)d_in[2];
    const float* zeros  = (const float*)d_in[3];
    const float* bias   = (const float*)d_in[4];
    float* out = (float*)d_out;

    const size_t wt_bytes = (size_t)OUT_F * IN_F * sizeof(unsigned short); // 90.2 MB
    const int grid_gemm = (M_TOTAL / 128) * (OUT_F / 128); // 64*86 = 5504

    if (ws_size >= wt_bytes) {
        unsigned short* wt = (unsigned short*)d_ws;
        dequant_w_kernel<<<dim3(OUT_F / 256, IN_F / 32), 256, 0, stream>>>(qw, scales, zeros, wt);
        gemm_kernel<true><<<grid_gemm, 256, 0, stream>>>(x, wt, qw, scales, zeros, bias, out);
    } else {
        gemm_kernel<false><<<grid_gemm, 256, 0, stream>>>(x, nullptr, qw, scales, zeros, bias, out);
    }
}

// Round 2
// 1185.133 us; speedup vs baseline: 1.1577x; 1.1577x over previous
//
#include <hip/hip_runtime.h>
#include <hip/hip_bf16.h>

#define IN_F 4096
#define OUT_F 11008
#define GSIZE 128
#define M_TOTAL 8192

typedef float f32x4 __attribute__((ext_vector_type(4)));
typedef unsigned short u16x8 __attribute__((ext_vector_type(8)));
typedef unsigned int u32x4 __attribute__((ext_vector_type(4)));
typedef __bf16 bf16x8 __attribute__((ext_vector_type(8)));

#define ASG __attribute__((address_space(1)))
#define ASL __attribute__((address_space(3)))

__device__ __forceinline__ unsigned short f2bf(float f) {
    union { float f; unsigned int u; } v;
    v.f = f;
    unsigned int u = v.u;
    unsigned int r = (u + 0x7fffu + ((u >> 16) & 1u)) >> 16;
    return (unsigned short)r;
}

// ---------------------------------------------------------------------------
// Pass 0: convert x fp32 -> bf16 [M][K] in ws. 16384 blocks x 256 thr x 8 elem.
// ---------------------------------------------------------------------------
__global__ void convert_x_kernel(const float* __restrict__ x,
                                 unsigned short* __restrict__ xb) {
    const size_t i = ((size_t)blockIdx.x * 256 + threadIdx.x) * 8;
    f32x4 a = *(const f32x4*)(x + i);
    f32x4 b = *(const f32x4*)(x + i + 4);
    u16x8 v;
#pragma unroll
    for (int e = 0; e < 4; ++e) {
        v[e]     = f2bf(a[e]);
        v[e + 4] = f2bf(b[e]);
    }
    *(u16x8*)(xb + i) = v;
}

// ---------------------------------------------------------------------------
// Pass 1: dequantize packed int4 weights -> W^T bf16 [OUT_F][IN_F] in ws.
// ---------------------------------------------------------------------------
__global__ void dequant_w_kernel(const int* __restrict__ qw,
                                 const float* __restrict__ scales,
                                 const float* __restrict__ zeros,
                                 unsigned short* __restrict__ wt) {
    const int n  = blockIdx.x * 256 + threadIdx.x;   // 0..11007
    const int k0 = blockIdx.y * 32;                  // 0..4064, step 32
    const int g  = k0 >> 7;
    const float s = scales[(size_t)g * OUT_F + n];
    const float z = zeros[(size_t)g * OUT_F + n];

    unsigned short outv[32];
#pragma unroll
    for (int i = 0; i < 16; ++i) {
        int q = qw[(size_t)(k0 / 2 + i) * OUT_F + n];
        float lo = (float)((q & 15) - 8) * s + z;        // even k = low nibble
        float hi = (float)(((q >> 4) & 15) - 8) * s + z; // odd k  = high nibble
        outv[2 * i]     = f2bf(lo);
        outv[2 * i + 1] = f2bf(hi);
    }
    u16x8* dst = (u16x8*)(wt + (size_t)n * IN_F + k0);
    const u16x8* src = (const u16x8*)outv;
#pragma unroll
    for (int i = 0; i < 4; ++i) dst[i] = src[i];
}

// ---------------------------------------------------------------------------
// Pass 2 (fast): bf16 GEMM, m97 structure.
// 128x128 tile, BK=64, 256 thr (4 waves, 2x2), 4x4 frags of 16x16x32 bf16.
// global_load_lds width=16 staging, linear LDS, XCD-swizzled blockIdx.
// ---------------------------------------------------------------------------
__global__ __launch_bounds__(256)
void gemm_fast(const unsigned short* __restrict__ xb,   // [M][K] bf16
               const unsigned short* __restrict__ wt,   // [N][K] bf16
               const float* __restrict__ bias,
               float* __restrict__ out) {
    constexpr int BK = 64;
    constexpr int NT = IN_F / BK;            // 64
    __shared__ unsigned short As[128 * BK];  // linear [128][64]
    __shared__ unsigned short Bs[128 * BK];

    constexpr int NB_N = OUT_F / 128;            // 86
    constexpr int NWG  = (M_TOTAL / 128) * NB_N; // 5504 (divisible by 8)
    constexpr int CPX  = NWG / 8;                // 688
    const int wg = (blockIdx.x % 8) * CPX + blockIdx.x / 8;
    const int m0 = (wg / NB_N) * 128;
    const int n0 = (wg % NB_N) * 128;

    const int tid  = threadIdx.x;
    const int lane = tid & 63;
    const int wave = tid >> 6;
    const int wr = wave >> 1, wc = wave & 1;

    // staging geometry: inst i of wave w covers LDS rows (w*4+i)*8 .. +8
    // lane l -> row +l/8, element col (l&7)*8 (16 B per lane, wave-linear dest)
    const int srow = lane >> 3;
    const int scol = (lane & 7) * 8;

    const unsigned short* ag[4];
    const unsigned short* bg[4];
    unsigned short* la[4];
    unsigned short* lb[4];
#pragma unroll
    for (int i = 0; i < 4; ++i) {
        const int rb = (wave * 4 + i) * 8;
        ag[i] = xb + (size_t)(m0 + rb + srow) * IN_F + scol;
        bg[i] = wt + (size_t)(n0 + rb + srow) * IN_F + scol;
        la[i] = &As[rb * BK];  // wave-uniform base; HW adds lane*16
        lb[i] = &Bs[rb * BK];
    }

    f32x4 acc[4][4];
#pragma unroll
    for (int i = 0; i < 4; ++i)
#pragma unroll
        for (int j = 0; j < 4; ++j) acc[i][j] = (f32x4)0.0f;

    const int kq = (lane >> 4) * 8;

#pragma unroll 1
    for (int kt = 0; kt < NT; ++kt) {
#pragma unroll
        for (int i = 0; i < 4; ++i) {
            __builtin_amdgcn_global_load_lds((ASG const unsigned int*)(ag[i]),
                                             (ASL unsigned int*)(la[i]), 16, 0, 0);
            __builtin_amdgcn_global_load_lds((ASG const unsigned int*)(bg[i]),
                                             (ASL unsigned int*)(lb[i]), 16, 0, 0);
            ag[i] += BK;
            bg[i] += BK;
        }
        __syncthreads();   // compiler drains vmcnt before barrier -> tile ready

#pragma unroll
        for (int kk = 0; kk < 2; ++kk) {
            const int kidx = kk * 32 + kq;
            bf16x8 af[4], bfv[4];
#pragma unroll
            for (int i = 0; i < 4; ++i)
                af[i] = *(const bf16x8*)(&As[(wr * 64 + i * 16 + (lane & 15)) * BK + kidx]);
#pragma unroll
            for (int j = 0; j < 4; ++j)
                bfv[j] = *(const bf16x8*)(&Bs[(wc * 64 + j * 16 + (lane & 15)) * BK + kidx]);
#pragma unroll
            for (int i = 0; i < 4; ++i)
#pragma unroll
                for (int j = 0; j < 4; ++j)
                    acc[i][j] = __builtin_amdgcn_mfma_f32_16x16x32_bf16(af[i], bfv[j], acc[i][j], 0, 0, 0);
        }
        __syncthreads();   // compute done before next stage overwrites LDS
    }

    // epilogue: C/D layout col = lane&15, row = (lane>>4)*4 + q
    const int orow_base = m0 + wr * 64 + ((lane >> 4) << 2);
    const int ocol_base = n0 + wc * 64 + (lane & 15);
#pragma unroll
    for (int j = 0; j < 4; ++j) {
        const float bv = bias[ocol_base + j * 16];
#pragma unroll
        for (int i = 0; i < 4; ++i) {
#pragma unroll
            for (int q = 0; q < 4; ++q) {
                out[(size_t)(orow_base + i * 16 + q) * OUT_F + (ocol_base + j * 16)] =
                    acc[i][j][q] + bv;
            }
        }
    }
}

// ---------------------------------------------------------------------------
// Fallback GEMM (round-1): reg-staged, fp32 x, PREW or dequant-on-fly.
// ---------------------------------------------------------------------------
template <bool PREW>
__global__ __launch_bounds__(256, 2)
void gemm_kernel(const float* __restrict__ x,
                 const unsigned short* __restrict__ wt,
                 const int* __restrict__ qw,
                 const float* __restrict__ scales,
                 const float* __restrict__ zeros,
                 const float* __restrict__ bias,
                 float* __restrict__ out) {
    constexpr int BM = 128, BN = 128, BK = 64;
    constexpr int LDK = BK + 8;
    constexpr int NT = IN_F / BK;

    __shared__ unsigned short As[BM * LDK];
    __shared__ unsigned short Bs[BN * LDK];

    const int bid = blockIdx.x;
    constexpr int NB_N = OUT_F / BN;
    const int m0 = (bid / NB_N) * BM;
    const int n0 = (bid % NB_N) * BN;

    const int tid  = threadIdx.x;
    const int lane = tid & 63;
    const int wave = tid >> 6;
    const int wr = wave >> 1, wc = wave & 1;

    const int st_row = tid >> 3;
    const int st_col = (tid & 7) * 8;

    f32x4 areg[4][2];
    u32x4 breg[4];
    int   qreg[16];
    float s_, z_;
    const int b_n  = tid & 127;
    const int b_kp = (tid >> 7) * 16;

    auto load_tile = [&](int kt) {
        {
            const float* base = x + (size_t)m0 * IN_F + (size_t)kt * BK + st_col;
#pragma unroll
            for (int p = 0; p < 4; ++p) {
                const float* rp = base + (size_t)(p * 32 + st_row) * IN_F;
                areg[p][0] = *(const f32x4*)rp;
                areg[p][1] = *(const f32x4*)(rp + 4);
            }
        }
        if constexpr (PREW) {
            const unsigned short* base = wt + (size_t)n0 * IN_F + (size_t)kt * BK + st_col;
#pragma unroll
            for (int p = 0; p < 4; ++p)
                breg[p] = *(const u32x4*)(base + (size_t)(p * 32 + st_row) * IN_F);
        } else {
            const int kp0 = kt * (BK / 2) + b_kp;
#pragma unroll
            for (int i = 0; i < 16; ++i)
                qreg[i] = qw[(size_t)(kp0 + i) * OUT_F + n0 + b_n];
            const int g = (kt * BK) >> 7;
            s_ = scales[(size_t)g * OUT_F + n0 + b_n];
            z_ = zeros[(size_t)g * OUT_F + n0 + b_n];
        }
    };

    auto write_lds = [&]() {
#pragma unroll
        for (int p = 0; p < 4; ++p) {
            u16x8 v;
#pragma unroll
            for (int e = 0; e < 4; ++e) {
                v[e]     = f2bf(areg[p][0][e]);
                v[e + 4] = f2bf(areg[p][1][e]);
            }
            *(u16x8*)(&As[(p * 32 + st_row) * LDK + st_col]) = v;
        }
        if constexpr (PREW) {
#pragma unroll
            for (int p = 0; p < 4; ++p)
                *(u32x4*)(&Bs[(p * 32 + st_row) * LDK + st_col]) = breg[p];
        } else {
            unsigned short tmp[32];
#pragma unroll
            for (int i = 0; i < 16; ++i) {
                int q = qreg[i];
                tmp[2 * i]     = f2bf((float)((q & 15) - 8) * s_ + z_);
                tmp[2 * i + 1] = f2bf((float)(((q >> 4) & 15) - 8) * s_ + z_);
            }
            const u16x8* srcv = (const u16x8*)tmp;
#pragma unroll
            for (int i = 0; i < 4; ++i)
                *(u16x8*)(&Bs[b_n * LDK + 2 * b_kp + 8 * i]) = srcv[i];
        }
    };

    f32x4 acc[4][4];
#pragma unroll
    for (int i = 0; i < 4; ++i)
#pragma unroll
        for (int j = 0; j < 4; ++j) acc[i][j] = (f32x4)0.0f;

    load_tile(0);

#pragma unroll 1
    for (int kt = 0; kt < NT; ++kt) {
        __syncthreads();
        write_lds();
        __syncthreads();
        if (kt + 1 < NT) load_tile(kt + 1);

#pragma unroll
        for (int kk = 0; kk < 2; ++kk) {
            const int kidx = kk * 32 + ((lane >> 4) << 3);
            bf16x8 af[4], bfv[4];
#pragma unroll
            for (int i = 0; i < 4; ++i)
                af[i] = *(const bf16x8*)(&As[(wr * 64 + i * 16 + (lane & 15)) * LDK + kidx]);
#pragma unroll
            for (int j = 0; j < 4; ++j)
                bfv[j] = *(const bf16x8*)(&Bs[(wc * 64 + j * 16 + (lane & 15)) * LDK + kidx]);
#pragma unroll
            for (int i = 0; i < 4; ++i)
#pragma unroll
                for (int j = 0; j < 4; ++j)
                    acc[i][j] = __builtin_amdgcn_mfma_f32_16x16x32_bf16(af[i], bfv[j], acc[i][j], 0, 0, 0);
        }
    }

    const int orow_base = m0 + wr * 64 + ((lane >> 4) << 2);
    const int ocol_base = n0 + wc * 64 + (lane & 15);
#pragma unroll
    for (int j = 0; j < 4; ++j) {
        const float bv = bias[ocol_base + j * 16];
#pragma unroll
        for (int i = 0; i < 4; ++i) {
#pragma unroll
            for (int q = 0; q < 4; ++q) {
                out[(size_t)(orow_base + i * 16 + q) * OUT_F + (ocol_base + j * 16)] =
                    acc[i][j][q] + bv;
            }
        }
    }
}

// ---------------------------------------------------------------------------
extern "C" void kernel_launch(void* const* d_in, const int* in_sizes, int n_in,
                              void* d_out, int out_size, void* d_ws, size_t ws_size,
                              hipStream_t stream) {
    const float* x      = (const float*)d_in[0];
    const int*   qw     = (const int*)d_in[1];
    const float* scales = (const float*)d_in[2];
    const float* zeros  = (const float*)d_in[3];
    const float* bias   = (const float*)d_in[4];
    float* out = (float*)d_out;

    const size_t wt_bytes = (size_t)OUT_F * IN_F * sizeof(unsigned short);   // 90.2 MB
    const size_t xb_bytes = (size_t)M_TOTAL * IN_F * sizeof(unsigned short); // 67.1 MB
    const int grid_gemm = (M_TOTAL / 128) * (OUT_F / 128); // 5504

    if (ws_size >= wt_bytes + xb_bytes) {
        unsigned short* wt = (unsigned short*)d_ws;
        unsigned short* xb = (unsigned short*)((char*)d_ws + wt_bytes);
        convert_x_kernel<<<(M_TOTAL * IN_F) / (256 * 8), 256, 0, stream>>>(x, xb);
        dequant_w_kernel<<<dim3(OUT_F / 256, IN_F / 32), 256, 0, stream>>>(qw, scales, zeros, wt);
        gemm_fast<<<grid_gemm, 256, 0, stream>>>(xb, wt, bias, out);
    } else if (ws_size >= wt_bytes) {
        unsigned short* wt = (unsigned short*)d_ws;
        dequant_w_kernel<<<dim3(OUT_F / 256, IN_F / 32), 256, 0, stream>>>(qw, scales, zeros, wt);
        gemm_kernel<true><<<grid_gemm, 256, 0, stream>>>(x, wt, qw, scales, zeros, bias, out);
    } else {
        gemm_kernel<false><<<grid_gemm, 256, 0, stream>>>(x, nullptr, qw, scales, zeros, bias, out);
    }
}

// Round 3
// 880.014 us; speedup vs baseline: 1.5591x; 1.3467x over previous
//
#include <hip/hip_runtime.h>
#include <hip/hip_bf16.h>

#define IN_F 4096
#define OUT_F 11008
#define GSIZE 128
#define M_TOTAL 8192

typedef float f32x4 __attribute__((ext_vector_type(4)));
typedef unsigned short u16x8 __attribute__((ext_vector_type(8)));
typedef unsigned int u32x4 __attribute__((ext_vector_type(4)));
typedef __bf16 bf16x8 __attribute__((ext_vector_type(8)));

#define ASG __attribute__((address_space(1)))
#define ASL __attribute__((address_space(3)))

__device__ __forceinline__ unsigned short f2bf(float f) {
    union { float f; unsigned int u; } v;
    v.f = f;
    unsigned int u = v.u;
    unsigned int r = (u + 0x7fffu + ((u >> 16) & 1u)) >> 16;
    return (unsigned short)r;
}

// ---------------------------------------------------------------------------
// Pass 0: convert x fp32 -> bf16 [M][K] in ws.
// ---------------------------------------------------------------------------
__global__ void convert_x_kernel(const float* __restrict__ x,
                                 unsigned short* __restrict__ xb) {
    const size_t i = ((size_t)blockIdx.x * 256 + threadIdx.x) * 8;
    f32x4 a = *(const f32x4*)(x + i);
    f32x4 b = *(const f32x4*)(x + i + 4);
    u16x8 v;
#pragma unroll
    for (int e = 0; e < 4; ++e) {
        v[e]     = f2bf(a[e]);
        v[e + 4] = f2bf(b[e]);
    }
    *(u16x8*)(xb + i) = v;
}

// ---------------------------------------------------------------------------
// Pass 1: dequantize packed int4 weights -> W^T bf16 [OUT_F][IN_F] in ws.
// ---------------------------------------------------------------------------
__global__ void dequant_w_kernel(const int* __restrict__ qw,
                                 const float* __restrict__ scales,
                                 const float* __restrict__ zeros,
                                 unsigned short* __restrict__ wt) {
    const int n  = blockIdx.x * 256 + threadIdx.x;
    const int k0 = blockIdx.y * 32;
    const int g  = k0 >> 7;
    const float s = scales[(size_t)g * OUT_F + n];
    const float z = zeros[(size_t)g * OUT_F + n];

    unsigned short outv[32];
#pragma unroll
    for (int i = 0; i < 16; ++i) {
        int q = qw[(size_t)(k0 / 2 + i) * OUT_F + n];
        float lo = (float)((q & 15) - 8) * s + z;        // even k = low nibble
        float hi = (float)(((q >> 4) & 15) - 8) * s + z; // odd k  = high nibble
        outv[2 * i]     = f2bf(lo);
        outv[2 * i + 1] = f2bf(hi);
    }
    u16x8* dst = (u16x8*)(wt + (size_t)n * IN_F + k0);
    const u16x8* src = (const u16x8*)outv;
#pragma unroll
    for (int i = 0; i < 4; ++i) dst[i] = src[i];
}

// ---------------------------------------------------------------------------
// Pass 2: 256x256 8-phase bf16 GEMM (m201-style template, plain HIP).
//  - 512 thr = 8 waves (2M x 4N); per-wave 128x64 out; BK=64; NT=64 K-tiles.
//  - LDS 128 KiB: 2 buffers x (A 32K + B 32K). Fragment-order subtiles:
//    each 16x32 MFMA operand tile stored as 1024 contiguous bytes, lane l's
//    fragment at +l*16 -> conflict-free ds_read_b128 AND linear gload_lds dest
//    (per-lane global src does the "swizzle" - m173 pattern).
//  - Per K-tile 4 phases: {ds_read subtile ; stage 1 half-tile ; barrier ;
//    16 MFMA @setprio(1) ; barrier}. Half-tile order (B0,B1,A0,A1) staggered
//    3-ahead; counted vmcnt(6) once per K-tile at phase 3 (T4).
// Hazard schedule (reads of buf p in tile t): B all @P0, A-mh0 @P0, A-mh1 @P2.
//  stage@t.P0: (t+1).A1 -> buf p^1 (last read: tile t-1)          OK
//  stage@t.P1: (t+2).B0 -> buf p   (B0 last read t.P0 < P1)       OK
//  stage@t.P2: (t+2).B1 -> buf p   (B1 last read t.P0 < P2)       OK
//  stage@t.P3: (t+2).A0 -> buf p   (A0 last read t.P2 < P3)       OK
// vmcnt(6) at t.P3 retires through (t+1).A1 => tile t+1 fully in LDS.
// ---------------------------------------------------------------------------
__global__ __launch_bounds__(512, 1)
void gemm_8phase(const unsigned short* __restrict__ xb,   // [M][K] bf16
                 const unsigned short* __restrict__ wt,   // [N][K] bf16
                 const float* __restrict__ bias,
                 float* __restrict__ out) {
    constexpr int NT = IN_F / 64;  // 64 K-tiles
    __shared__ __attribute__((aligned(128))) unsigned short lds[65536]; // 128 KiB

    constexpr int NB_N = OUT_F / 256;             // 43
    constexpr int NWG  = (M_TOTAL / 256) * NB_N;  // 1376 (divisible by 8)
    constexpr int CPX  = NWG / 8;                 // 172
    const int wg = ((int)blockIdx.x % 8) * CPX + (int)blockIdx.x / 8;
    const int m0 = (wg / NB_N) * 256;
    const int n0 = (wg % NB_N) * 256;

    const int tid  = threadIdx.x;
    const int lane = tid & 63;
    const int wave = tid >> 6;       // 0..7
    const int wr = wave >> 2;        // 0..1  (M)
    const int wc = wave & 3;         // 0..3  (N)
    const int r16 = lane & 15;
    const int q4  = lane >> 4;

    // ---- staging: half-tile H of A/B for K-tile T into buf (T&1).
    // wave w, inst i covers subtile s = i*8+w of the half-tile
    // (frag f = s>>1, k-chunk kc = s&1); dest linear, src per-lane fragment.
#define STAGE_A(T, H)                                                          \
    do {                                                                       \
        const int _p = (T) & 1;                                                \
        _Pragma("unroll") for (int _i = 0; _i < 2; ++_i) {                     \
            const int _s = _i * 8 + wave;                                      \
            const int _f = _s >> 1, _kc = _s & 1;                              \
            const unsigned short* _src = xb +                                  \
                (size_t)(m0 + (H) * 128 + _f * 16 + r16) * IN_F +              \
                (size_t)(T) * 64 + _kc * 32 + q4 * 8;                          \
            unsigned short* _dst = lds + _p * 32768 + ((H) * 16 + _s) * 512;   \
            __builtin_amdgcn_global_load_lds((ASG const unsigned int*)_src,    \
                                             (ASL unsigned int*)_dst, 16, 0, 0);\
        }                                                                      \
    } while (0)

#define STAGE_B(T, H)                                                          \
    do {                                                                       \
        const int _p = (T) & 1;                                                \
        _Pragma("unroll") for (int _i = 0; _i < 2; ++_i) {                     \
            const int _s = _i * 8 + wave;                                      \
            const int _f = _s >> 1, _kc = _s & 1;                              \
            const unsigned short* _src = wt +                                  \
                (size_t)(n0 + (H) * 128 + _f * 16 + r16) * IN_F +              \
                (size_t)(T) * 64 + _kc * 32 + q4 * 8;                          \
            unsigned short* _dst = lds + _p * 32768 + 16384 +                  \
                                   ((H) * 16 + _s) * 512;                      \
            __builtin_amdgcn_global_load_lds((ASG const unsigned int*)_src,    \
                                             (ASL unsigned int*)_dst, 16, 0, 0);\
        }                                                                      \
    } while (0)

    bf16x8 af[4][2];   // wave's current M-half: 4 frags x 2 k-chunks
    bf16x8 bf[4][2];   // wave's 4 N-frags x 2 k-chunks (held whole tile)
    f32x4  acc[8][4];
#pragma unroll
    for (int i = 0; i < 8; ++i)
#pragma unroll
        for (int j = 0; j < 4; ++j) acc[i][j] = (f32x4)0.0f;

#define READ_A(P, MH)                                                          \
    do {                                                                       \
        const unsigned short* _ab = lds + (P) * 32768 + lane * 8;              \
        _Pragma("unroll") for (int _ii = 0; _ii < 4; ++_ii)                    \
        _Pragma("unroll") for (int _kc = 0; _kc < 2; ++_kc)                    \
            af[_ii][_kc] = *(const bf16x8*)(_ab +                              \
                (((wr * 8 + (MH) * 4 + _ii) * 2 + _kc) << 9));                 \
    } while (0)

#define READ_B(P)                                                              \
    do {                                                                       \
        const unsigned short* _bb = lds + (P) * 32768 + 16384 + lane * 8;      \
        _Pragma("unroll") for (int _g = 0; _g < 4; ++_g)                       \
        _Pragma("unroll") for (int _kc = 0; _kc < 2; ++_kc)                    \
            bf[_g][_kc] = *(const bf16x8*)(_bb +                               \
                (((wc * 4 + _g) * 2 + _kc) << 9));                             \
    } while (0)

#define QUAD(MH, NH)                                                           \
    do {                                                                       \
        __builtin_amdgcn_s_setprio(1);                                         \
        _Pragma("unroll") for (int _ii = 0; _ii < 4; ++_ii)                    \
        _Pragma("unroll") for (int _g = 0; _g < 2; ++_g)                       \
        _Pragma("unroll") for (int _kc = 0; _kc < 2; ++_kc)                    \
            acc[(MH) * 4 + _ii][(NH) * 2 + _g] =                               \
                __builtin_amdgcn_mfma_f32_16x16x32_bf16(                       \
                    af[_ii][_kc], bf[(NH) * 2 + _g][_kc],                      \
                    acc[(MH) * 4 + _ii][(NH) * 2 + _g], 0, 0, 0);              \
        __builtin_amdgcn_s_setprio(0);                                         \
    } while (0)

    // ---- prologue: tile0 {B0,B1,A0,A1}, tile1 {B0,B1,A0}; keep 6 in flight
    STAGE_B(0, 0); STAGE_B(0, 1); STAGE_A(0, 0); STAGE_A(0, 1);
    STAGE_B(1, 0); STAGE_B(1, 1); STAGE_A(1, 0);
    asm volatile("s_waitcnt vmcnt(6)" ::: "memory");
    __builtin_amdgcn_s_barrier();

#pragma unroll 1
    for (int t = 0; t < NT; ++t) {
        const int p = t & 1;
        // ---- P0: Q(mh0,nh0)
        READ_A(p, 0);
        READ_B(p);
        if (t + 1 < NT) STAGE_A(t + 1, 1);          // (t+1).h4 = A1 -> buf p^1
        __builtin_amdgcn_s_barrier();
        QUAD(0, 0);
        __builtin_amdgcn_s_barrier();
        // ---- P1: Q(mh0,nh1)
        if (t + 2 < NT) STAGE_B(t + 2, 0);          // (t+2).h1 = B0 -> buf p
        __builtin_amdgcn_s_barrier();
        QUAD(0, 1);
        __builtin_amdgcn_s_barrier();
        // ---- P2: Q(mh1,nh0)
        READ_A(p, 1);
        if (t + 2 < NT) STAGE_B(t + 2, 1);          // (t+2).h2 = B1 -> buf p
        __builtin_amdgcn_s_barrier();
        QUAD(1, 0);
        __builtin_amdgcn_s_barrier();
        // ---- P3: Q(mh1,nh1)
        if (t + 2 < NT) STAGE_A(t + 2, 0);          // (t+2).h3 = A0 -> buf p
        if (t < NT - 2) {
            asm volatile("s_waitcnt vmcnt(6)" ::: "memory");  // counted (T4)
        } else {
            asm volatile("s_waitcnt vmcnt(0)" ::: "memory");  // epilogue drain
        }
        __builtin_amdgcn_s_barrier();
        QUAD(1, 1);
        __builtin_amdgcn_s_barrier();
    }

    // ---- epilogue: C/D col = lane&15, row = (lane>>4)*4 + q
#pragma unroll
    for (int g = 0; g < 4; ++g) {
        const int col = n0 + wc * 64 + g * 16 + r16;
        const float bv = bias[col];
#pragma unroll
        for (int fl = 0; fl < 8; ++fl) {
            const int row0 = m0 + wr * 128 + fl * 16 + q4 * 4;
#pragma unroll
            for (int qq = 0; qq < 4; ++qq)
                out[(size_t)(row0 + qq) * OUT_F + col] = acc[fl][g][qq] + bv;
        }
    }
#undef STAGE_A
#undef STAGE_B
#undef READ_A
#undef READ_B
#undef QUAD
}

// ---------------------------------------------------------------------------
// Fallback GEMM (reg-staged 128x128), for small ws.
// ---------------------------------------------------------------------------
template <bool PREW>
__global__ __launch_bounds__(256, 2)
void gemm_kernel(const float* __restrict__ x,
                 const unsigned short* __restrict__ wt,
                 const int* __restrict__ qw,
                 const float* __restrict__ scales,
                 const float* __restrict__ zeros,
                 const float* __restrict__ bias,
                 float* __restrict__ out) {
    constexpr int BM = 128, BN = 128, BK = 64;
    constexpr int LDK = BK + 8;
    constexpr int NT = IN_F / BK;

    __shared__ unsigned short As[BM * LDK];
    __shared__ unsigned short Bs[BN * LDK];

    const int bid = blockIdx.x;
    constexpr int NB_N = OUT_F / BN;
    const int m0 = (bid / NB_N) * BM;
    const int n0 = (bid % NB_N) * BN;

    const int tid  = threadIdx.x;
    const int lane = tid & 63;
    const int wave = tid >> 6;
    const int wr = wave >> 1, wc = wave & 1;

    const int st_row = tid >> 3;
    const int st_col = (tid & 7) * 8;

    f32x4 areg[4][2];
    u32x4 breg[4];
    int   qreg[16];
    float s_, z_;
    const int b_n  = tid & 127;
    const int b_kp = (tid >> 7) * 16;

    auto load_tile = [&](int kt) {
        {
            const float* base = x + (size_t)m0 * IN_F + (size_t)kt * BK + st_col;
#pragma unroll
            for (int p = 0; p < 4; ++p) {
                const float* rp = base + (size_t)(p * 32 + st_row) * IN_F;
                areg[p][0] = *(const f32x4*)rp;
                areg[p][1] = *(const f32x4*)(rp + 4);
            }
        }
        if constexpr (PREW) {
            const unsigned short* base = wt + (size_t)n0 * IN_F + (size_t)kt * BK + st_col;
#pragma unroll
            for (int p = 0; p < 4; ++p)
                breg[p] = *(const u32x4*)(base + (size_t)(p * 32 + st_row) * IN_F);
        } else {
            const int kp0 = kt * (BK / 2) + b_kp;
#pragma unroll
            for (int i = 0; i < 16; ++i)
                qreg[i] = qw[(size_t)(kp0 + i) * OUT_F + n0 + b_n];
            const int g = (kt * BK) >> 7;
            s_ = scales[(size_t)g * OUT_F + n0 + b_n];
            z_ = zeros[(size_t)g * OUT_F + n0 + b_n];
        }
    };

    auto write_lds = [&]() {
#pragma unroll
        for (int p = 0; p < 4; ++p) {
            u16x8 v;
#pragma unroll
            for (int e = 0; e < 4; ++e) {
                v[e]     = f2bf(areg[p][0][e]);
                v[e + 4] = f2bf(areg[p][1][e]);
            }
            *(u16x8*)(&As[(p * 32 + st_row) * LDK + st_col]) = v;
        }
        if constexpr (PREW) {
#pragma unroll
            for (int p = 0; p < 4; ++p)
                *(u32x4*)(&Bs[(p * 32 + st_row) * LDK + st_col]) = breg[p];
        } else {
            unsigned short tmp[32];
#pragma unroll
            for (int i = 0; i < 16; ++i) {
                int q = qreg[i];
                tmp[2 * i]     = f2bf((float)((q & 15) - 8) * s_ + z_);
                tmp[2 * i + 1] = f2bf((float)(((q >> 4) & 15) - 8) * s_ + z_);
            }
            const u16x8* srcv = (const u16x8*)tmp;
#pragma unroll
            for (int i = 0; i < 4; ++i)
                *(u16x8*)(&Bs[b_n * LDK + 2 * b_kp + 8 * i]) = srcv[i];
        }
    };

    f32x4 acc[4][4];
#pragma unroll
    for (int i = 0; i < 4; ++i)
#pragma unroll
        for (int j = 0; j < 4; ++j) acc[i][j] = (f32x4)0.0f;

    load_tile(0);

#pragma unroll 1
    for (int kt = 0; kt < NT; ++kt) {
        __syncthreads();
        write_lds();
        __syncthreads();
        if (kt + 1 < NT) load_tile(kt + 1);

#pragma unroll
        for (int kk = 0; kk < 2; ++kk) {
            const int kidx = kk * 32 + ((lane >> 4) << 3);
            bf16x8 afv[4], bfv[4];
#pragma unroll
            for (int i = 0; i < 4; ++i)
                afv[i] = *(const bf16x8*)(&As[(wr * 64 + i * 16 + (lane & 15)) * LDK + kidx]);
#pragma unroll
            for (int j = 0; j < 4; ++j)
                bfv[j] = *(const bf16x8*)(&Bs[(wc * 64 + j * 16 + (lane & 15)) * LDK + kidx]);
#pragma unroll
            for (int i = 0; i < 4; ++i)
#pragma unroll
                for (int j = 0; j < 4; ++j)
                    acc[i][j] = __builtin_amdgcn_mfma_f32_16x16x32_bf16(afv[i], bfv[j], acc[i][j], 0, 0, 0);
        }
    }

    const int orow_base = m0 + wr * 64 + ((lane >> 4) << 2);
    const int ocol_base = n0 + wc * 64 + (lane & 15);
#pragma unroll
    for (int j = 0; j < 4; ++j) {
        const float bv = bias[ocol_base + j * 16];
#pragma unroll
        for (int i = 0; i < 4; ++i) {
#pragma unroll
            for (int q = 0; q < 4; ++q) {
                out[(size_t)(orow_base + i * 16 + q) * OUT_F + (ocol_base + j * 16)] =
                    acc[i][j][q] + bv;
            }
        }
    }
}

// ---------------------------------------------------------------------------
extern "C" void kernel_launch(void* const* d_in, const int* in_sizes, int n_in,
                              void* d_out, int out_size, void* d_ws, size_t ws_size,
                              hipStream_t stream) {
    const float* x      = (const float*)d_in[0];
    const int*   qw     = (const int*)d_in[1];
    const float* scales = (const float*)d_in[2];
    const float* zeros  = (const float*)d_in[3];
    const float* bias   = (const float*)d_in[4];
    float* out = (float*)d_out;

    const size_t wt_bytes = (size_t)OUT_F * IN_F * sizeof(unsigned short);   // 90.2 MB
    const size_t xb_bytes = (size_t)M_TOTAL * IN_F * sizeof(unsigned short); // 67.1 MB

    if (ws_size >= wt_bytes + xb_bytes) {
        unsigned short* wt = (unsigned short*)d_ws;
        unsigned short* xb = (unsigned short*)((char*)d_ws + wt_bytes);
        convert_x_kernel<<<(M_TOTAL * IN_F) / (256 * 8), 256, 0, stream>>>(x, xb);
        dequant_w_kernel<<<dim3(OUT_F / 256, IN_F / 32), 256, 0, stream>>>(qw, scales, zeros, wt);
        gemm_8phase<<<(M_TOTAL / 256) * (OUT_F / 256), 512, 0, stream>>>(xb, wt, bias, out);
    } else if (ws_size >= wt_bytes) {
        unsigned short* wt = (unsigned short*)d_ws;
        dequant_w_kernel<<<dim3(OUT_F / 256, IN_F / 32), 256, 0, stream>>>(qw, scales, zeros, wt);
        gemm_kernel<true><<<(M_TOTAL / 128) * (OUT_F / 128), 256, 0, stream>>>(x, wt, qw, scales, zeros, bias, out);
    } else {
        gemm_kernel<false><<<(M_TOTAL / 128) * (OUT_F / 128), 256, 0, stream>>>(x, nullptr, qw, scales, zeros, bias, out);
    }
}

// Round 5
// 872.702 us; speedup vs baseline: 1.5721x; 1.0084x over previous
//
#include <hip/hip_runtime.h>
#include <hip/hip_bf16.h>

#define IN_F 4096
#define OUT_F 11008
#define GSIZE 128
#define M_TOTAL 8192

typedef float f32x4 __attribute__((ext_vector_type(4)));
typedef unsigned short u16x8 __attribute__((ext_vector_type(8)));
typedef unsigned int u32x4 __attribute__((ext_vector_type(4)));
typedef __bf16 bf16x8 __attribute__((ext_vector_type(8)));

#define ASG __attribute__((address_space(1)))
#define ASL __attribute__((address_space(3)))

__device__ __forceinline__ unsigned short f2bf(float f) {
    union { float f; unsigned int u; } v;
    v.f = f;
    unsigned int u = v.u;
    unsigned int r = (u + 0x7fffu + ((u >> 16) & 1u)) >> 16;
    return (unsigned short)r;
}

// ---------------------------------------------------------------------------
// Pass 0: convert x fp32 -> bf16 [M][K] in ws.
// ---------------------------------------------------------------------------
__global__ void convert_x_kernel(const float* __restrict__ x,
                                 unsigned short* __restrict__ xb) {
    const size_t i = ((size_t)blockIdx.x * 256 + threadIdx.x) * 8;
    f32x4 a = *(const f32x4*)(x + i);
    f32x4 b = *(const f32x4*)(x + i + 4);
    u16x8 v;
#pragma unroll
    for (int e = 0; e < 4; ++e) {
        v[e]     = f2bf(a[e]);
        v[e + 4] = f2bf(b[e]);
    }
    *(u16x8*)(xb + i) = v;
}

// ---------------------------------------------------------------------------
// Pass 1: dequantize packed int4 weights -> W^T bf16 [OUT_F][IN_F] in ws.
// ---------------------------------------------------------------------------
__global__ void dequant_w_kernel(const int* __restrict__ qw,
                                 const float* __restrict__ scales,
                                 const float* __restrict__ zeros,
                                 unsigned short* __restrict__ wt) {
    const int n  = blockIdx.x * 256 + threadIdx.x;
    const int k0 = blockIdx.y * 32;
    const int g  = k0 >> 7;
    const float s = scales[(size_t)g * OUT_F + n];
    const float z = zeros[(size_t)g * OUT_F + n];

    unsigned short outv[32];
#pragma unroll
    for (int i = 0; i < 16; ++i) {
        int q = qw[(size_t)(k0 / 2 + i) * OUT_F + n];
        float lo = (float)((q & 15) - 8) * s + z;        // even k = low nibble
        float hi = (float)(((q >> 4) & 15) - 8) * s + z; // odd k  = high nibble
        outv[2 * i]     = f2bf(lo);
        outv[2 * i + 1] = f2bf(hi);
    }
    u16x8* dst = (u16x8*)(wt + (size_t)n * IN_F + k0);
    const u16x8* src = (const u16x8*)outv;
#pragma unroll
    for (int i = 0; i < 4; ++i) dst[i] = src[i];
}

// ---------------------------------------------------------------------------
// Pass 2: 256x256 8-phase bf16 GEMM.
// Round-5: round-3's PASSING 2-barrier-per-phase schedule, plus:
//  - hard region fences: sched_barrier(0) around every s_barrier and before
//    each vmcnt asm. Raw s_barrier is IntrNoMem -> compiler may otherwise
//    move LDS reads/stage intrinsics across it (round-4 NaN mechanism:
//    reads hoisted above the barrier race other waves' cooperative stages).
//  - hoisted staging addresses: 8 per-thread 32-bit byte-offset streams,
//    advanced +128 after each use. No muls, no imm-offset tricks in loop.
//  - 2-tile unrolled body (compile-time buffer parity).
// Schedule per tile t (buf p), phases P0..P3, each = [work] bar [QUAD] bar:
//  P0: read A-H0 + all B (buf p); stage A1(t+1)->buf !p        | Q(0,0)
//  P1: stage B0(t+2)->buf p                                    | Q(0,1)
//  P2: read A-H1 (buf p); stage B1(t+2)->buf p                 | Q(1,0)
//  P3: stage A0(t+2)->buf p; vmcnt(6)                          | Q(1,1)
// WAR: every stage follows its region's last reader by >=1 barrier.
// RAW: vmcnt(6) at P3 retires the 8 oldest of 14 in-flight stage insts =
//      all of tile t+1 -> after the barrier, tile t+1 fully resident.
// ---------------------------------------------------------------------------
__global__ __launch_bounds__(512, 1)
void gemm_8phase(const unsigned short* __restrict__ xb,   // [M][K] bf16
                 const unsigned short* __restrict__ wt,   // [N][K] bf16
                 const float* __restrict__ bias,
                 float* __restrict__ out) {
    constexpr int NT = IN_F / 64;  // 64 K-tiles
    __shared__ __attribute__((aligned(128))) unsigned short lds[65536]; // 128 KiB

    constexpr int NB_N = OUT_F / 256;             // 43
    constexpr int NWG  = (M_TOTAL / 256) * NB_N;  // 1376 (divisible by 8)
    constexpr int CPX  = NWG / 8;                 // 172
    const int wg = ((int)blockIdx.x % 8) * CPX + (int)blockIdx.x / 8;
    const int m0 = (wg / NB_N) * 256;
    const int n0 = (wg % NB_N) * 256;

    const int tid  = threadIdx.x;
    const int lane = tid & 63;
    const int wave = tid >> 6;       // 0..7
    const int wr = wave >> 2;        // 0..1  (M)
    const int wc = wave & 3;         // 0..3  (N)
    const int r16 = lane & 15;
    const int q4  = lane >> 4;

    const ASG char* xbc = (const ASG char*)xb;
    const ASG char* wtc = (const ASG char*)wt;
    ASL char* ldsc = (ASL char*)lds;

    // ---- 8 staging streams: per-thread 32-bit global byte offsets and
    // wave-uniform LDS dest byte offsets. Stream idx = HS*2 + i; stream HS
    // always stages half HS. Subtile s = i*8+wave (f = s>>1, kc = s&1).
    unsigned int oA[4], oB[4];
    int dA[4], dB[4];
#pragma unroll
    for (int H = 0; H < 2; ++H)
#pragma unroll
        for (int i = 0; i < 2; ++i) {
            const int s = i * 8 + wave;
            const int f = s >> 1, kc = s & 1;
            oA[H * 2 + i] = (unsigned int)(((m0 + H * 128 + f * 16 + r16) * IN_F +
                                            kc * 32 + q4 * 8) * 2);
            oB[H * 2 + i] = (unsigned int)(((n0 + H * 128 + f * 16 + r16) * IN_F +
                                            kc * 32 + q4 * 8) * 2);
            dA[H * 2 + i] = (H * 16 + s) * 1024;
            dB[H * 2 + i] = 32768 + (H * 16 + s) * 1024;
        }

#define STGA_LOADS(HS, P)                                                      \
    do {                                                                       \
        _Pragma("unroll") for (int _i = 0; _i < 2; ++_i)                       \
            __builtin_amdgcn_global_load_lds(                                  \
                (ASG const unsigned int*)(xbc + oA[(HS) * 2 + _i]),            \
                (ASL unsigned int*)(ldsc + dA[(HS) * 2 + _i] + (P) * 65536),   \
                16, 0, 0);                                                     \
    } while (0)
#define STGB_LOADS(HS, P)                                                      \
    do {                                                                       \
        _Pragma("unroll") for (int _i = 0; _i < 2; ++_i)                       \
            __builtin_amdgcn_global_load_lds(                                  \
                (ASG const unsigned int*)(wtc + oB[(HS) * 2 + _i]),            \
                (ASL unsigned int*)(ldsc + dB[(HS) * 2 + _i] + (P) * 65536),   \
                16, 0, 0);                                                     \
    } while (0)
#define ADV_A(HS) do { oA[(HS)*2] += 128; oA[(HS)*2+1] += 128; } while (0)
#define ADV_B(HS) do { oB[(HS)*2] += 128; oB[(HS)*2+1] += 128; } while (0)

// hard region boundary: nothing schedules across the barrier
#define BAR()                                                                  \
    do {                                                                       \
        __builtin_amdgcn_sched_barrier(0);                                     \
        __builtin_amdgcn_s_barrier();                                          \
        __builtin_amdgcn_sched_barrier(0);                                     \
    } while (0)

    bf16x8 af[4][2];   // current M-half: 4 frags x 2 k-chunks
    bf16x8 bf[4][2];   // 4 N-frags x 2 k-chunks (held whole tile)
    f32x4  acc[8][4];
#pragma unroll
    for (int i = 0; i < 8; ++i)
#pragma unroll
        for (int j = 0; j < 4; ++j) acc[i][j] = (f32x4)0.0f;

#define READ_A(P, MH)                                                          \
    do {                                                                       \
        const unsigned short* _ab = lds + (P) * 32768 + lane * 8;              \
        _Pragma("unroll") for (int _ii = 0; _ii < 4; ++_ii)                    \
        _Pragma("unroll") for (int _kc = 0; _kc < 2; ++_kc)                    \
            af[_ii][_kc] = *(const bf16x8*)(_ab +                              \
                (((wr * 8 + (MH) * 4 + _ii) * 2 + _kc) << 9));                 \
    } while (0)

#define READ_B(P)                                                              \
    do {                                                                       \
        const unsigned short* _bb = lds + (P) * 32768 + 16384 + lane * 8;      \
        _Pragma("unroll") for (int _g = 0; _g < 4; ++_g)                       \
        _Pragma("unroll") for (int _kc = 0; _kc < 2; ++_kc)                    \
            bf[_g][_kc] = *(const bf16x8*)(_bb +                               \
                (((wc * 4 + _g) * 2 + _kc) << 9));                             \
    } while (0)

#define QUAD(MH, NH)                                                           \
    do {                                                                       \
        __builtin_amdgcn_s_setprio(1);                                         \
        _Pragma("unroll") for (int _ii = 0; _ii < 4; ++_ii)                    \
        _Pragma("unroll") for (int _g = 0; _g < 2; ++_g)                       \
        _Pragma("unroll") for (int _kc = 0; _kc < 2; ++_kc)                    \
            acc[(MH) * 4 + _ii][(NH) * 2 + _g] =                               \
                __builtin_amdgcn_mfma_f32_16x16x32_bf16(                       \
                    af[_ii][_kc], bf[(NH) * 2 + _g][_kc],                      \
                    acc[(MH) * 4 + _ii][(NH) * 2 + _g], 0, 0, 0);              \
        __builtin_amdgcn_s_setprio(0);                                         \
    } while (0)

    // ---- prologue: tile0 {B0,B1,A0,A1}, tile1 {B0,B1,A0}; 6 left in flight.
    STGB_LOADS(0, 0); ADV_B(0);   // B0(0)
    STGB_LOADS(1, 0); ADV_B(1);   // B1(0)
    STGA_LOADS(0, 0); ADV_A(0);   // A0(0)
    STGA_LOADS(1, 0); ADV_A(1);   // A1(0)  -> A1 stream now T=1
    STGB_LOADS(0, 1); ADV_B(0);   // B0(1)  -> T=2
    STGB_LOADS(1, 1); ADV_B(1);   // B1(1)  -> T=2
    STGA_LOADS(0, 1); ADV_A(0);   // A0(1)  -> T=2
    __builtin_amdgcn_sched_barrier(0);
    asm volatile("s_waitcnt vmcnt(6)" ::: "memory");  // tile0 resident
    BAR();

#pragma unroll 1
    for (int tt = 0; tt < NT; tt += 2) {
        const bool g2 = (tt + 2 < NT);
        const bool g3 = (tt + 3 < NT);
        // ================= tile tt (buf 0) =================
        // P0
        READ_A(0, 0);
        READ_B(0);
        STGA_LOADS(1, 1); ADV_A(1);              // A1(tt+1) -> buf1
        BAR();
        QUAD(0, 0);
        BAR();
        // P1
        if (g2) STGB_LOADS(0, 0);
        ADV_B(0);                                 // B0(tt+2) -> buf0
        BAR();
        QUAD(0, 1);
        BAR();
        // P2
        READ_A(0, 1);
        if (g2) STGB_LOADS(1, 0);
        ADV_B(1);                                 // B1(tt+2) -> buf0
        BAR();
        QUAD(1, 0);
        BAR();
        // P3
        if (g2) STGA_LOADS(0, 0);
        ADV_A(0);                                 // A0(tt+2) -> buf0
        __builtin_amdgcn_sched_barrier(0);
        if (tt < NT - 2) {
            asm volatile("s_waitcnt vmcnt(6)" ::: "memory");
        } else {
            asm volatile("s_waitcnt vmcnt(0)" ::: "memory");
        }
        BAR();
        QUAD(1, 1);
        BAR();
        // ================= tile tt+1 (buf 1) =================
        // P0
        READ_A(1, 0);
        READ_B(1);
        if (g2) STGA_LOADS(1, 0);
        ADV_A(1);                                 // A1(tt+2) -> buf0
        BAR();
        QUAD(0, 0);
        BAR();
        // P1
        if (g3) STGB_LOADS(0, 1);
        ADV_B(0);                                 // B0(tt+3) -> buf1
        BAR();
        QUAD(0, 1);
        BAR();
        // P2
        READ_A(1, 1);
        if (g3) STGB_LOADS(1, 1);
        ADV_B(1);                                 // B1(tt+3) -> buf1
        BAR();
        QUAD(1, 0);
        BAR();
        // P3
        if (g3) STGA_LOADS(0, 1);
        ADV_A(0);                                 // A0(tt+3) -> buf1
        __builtin_amdgcn_sched_barrier(0);
        if (tt + 1 < NT - 2) {
            asm volatile("s_waitcnt vmcnt(6)" ::: "memory");
        } else {
            asm volatile("s_waitcnt vmcnt(0)" ::: "memory");
        }
        BAR();
        QUAD(1, 1);
        BAR();
    }

    // ---- epilogue: C/D col = lane&15, row = (lane>>4)*4 + q
#pragma unroll
    for (int g = 0; g < 4; ++g) {
        const int col = n0 + wc * 64 + g * 16 + r16;
        const float bv = bias[col];
#pragma unroll
        for (int fl = 0; fl < 8; ++fl) {
            const int row0 = m0 + wr * 128 + fl * 16 + q4 * 4;
#pragma unroll
            for (int qq = 0; qq < 4; ++qq)
                out[(size_t)(row0 + qq) * OUT_F + col] = acc[fl][g][qq] + bv;
        }
    }
#undef STGA_LOADS
#undef STGB_LOADS
#undef ADV_A
#undef ADV_B
#undef BAR
#undef READ_A
#undef READ_B
#undef QUAD
}

// ---------------------------------------------------------------------------
// Fallback GEMM (reg-staged 128x128), for small ws.
// ---------------------------------------------------------------------------
template <bool PREW>
__global__ __launch_bounds__(256, 2)
void gemm_kernel(const float* __restrict__ x,
                 const unsigned short* __restrict__ wt,
                 const int* __restrict__ qw,
                 const float* __restrict__ scales,
                 const float* __restrict__ zeros,
                 const float* __restrict__ bias,
                 float* __restrict__ out) {
    constexpr int BM = 128, BN = 128, BK = 64;
    constexpr int LDK = BK + 8;
    constexpr int NT = IN_F / BK;

    __shared__ unsigned short As[BM * LDK];
    __shared__ unsigned short Bs[BN * LDK];

    const int bid = blockIdx.x;
    constexpr int NB_N = OUT_F / BN;
    const int m0 = (bid / NB_N) * BM;
    const int n0 = (bid % NB_N) * BN;

    const int tid  = threadIdx.x;
    const int lane = tid & 63;
    const int wave = tid >> 6;
    const int wr = wave >> 1, wc = wave & 1;

    const int st_row = tid >> 3;
    const int st_col = (tid & 7) * 8;

    f32x4 areg[4][2];
    u32x4 breg[4];
    int   qreg[16];
    float s_, z_;
    const int b_n  = tid & 127;
    const int b_kp = (tid >> 7) * 16;

    auto load_tile = [&](int kt) {
        {
            const float* base = x + (size_t)m0 * IN_F + (size_t)kt * BK + st_col;
#pragma unroll
            for (int p = 0; p < 4; ++p) {
                const float* rp = base + (size_t)(p * 32 + st_row) * IN_F;
                areg[p][0] = *(const f32x4*)rp;
                areg[p][1] = *(const f32x4*)(rp + 4);
            }
        }
        if constexpr (PREW) {
            const unsigned short* base = wt + (size_t)n0 * IN_F + (size_t)kt * BK + st_col;
#pragma unroll
            for (int p = 0; p < 4; ++p)
                breg[p] = *(const u32x4*)(base + (size_t)(p * 32 + st_row) * IN_F);
        } else {
            const int kp0 = kt * (BK / 2) + b_kp;
#pragma unroll
            for (int i = 0; i < 16; ++i)
                qreg[i] = qw[(size_t)(kp0 + i) * OUT_F + n0 + b_n];
            const int g = (kt * BK) >> 7;
            s_ = scales[(size_t)g * OUT_F + n0 + b_n];
            z_ = zeros[(size_t)g * OUT_F + n0 + b_n];
        }
    };

    auto write_lds = [&]() {
#pragma unroll
        for (int p = 0; p < 4; ++p) {
            u16x8 v;
#pragma unroll
            for (int e = 0; e < 4; ++e) {
                v[e]     = f2bf(areg[p][0][e]);
                v[e + 4] = f2bf(areg[p][1][e]);
            }
            *(u16x8*)(&As[(p * 32 + st_row) * LDK + st_col]) = v;
        }
        if constexpr (PREW) {
#pragma unroll
            for (int p = 0; p < 4; ++p)
                *(u32x4*)(&Bs[(p * 32 + st_row) * LDK + st_col]) = breg[p];
        } else {
            unsigned short tmp[32];
#pragma unroll
            for (int i = 0; i < 16; ++i) {
                int q = qreg[i];
                tmp[2 * i]     = f2bf((float)((q & 15) - 8) * s_ + z_);
                tmp[2 * i + 1] = f2bf((float)(((q >> 4) & 15) - 8) * s_ + z_);
            }
            const u16x8* srcv = (const u16x8*)tmp;
#pragma unroll
            for (int i = 0; i < 4; ++i)
                *(u16x8*)(&Bs[b_n * LDK + 2 * b_kp + 8 * i]) = srcv[i];
        }
    };

    f32x4 acc[4][4];
#pragma unroll
    for (int i = 0; i < 4; ++i)
#pragma unroll
        for (int j = 0; j < 4; ++j) acc[i][j] = (f32x4)0.0f;

    load_tile(0);

#pragma unroll 1
    for (int kt = 0; kt < NT; ++kt) {
        __syncthreads();
        write_lds();
        __syncthreads();
        if (kt + 1 < NT) load_tile(kt + 1);

#pragma unroll
        for (int kk = 0; kk < 2; ++kk) {
            const int kidx = kk * 32 + ((lane >> 4) << 3);
            bf16x8 afv[4], bfv[4];
#pragma unroll
            for (int i = 0; i < 4; ++i)
                afv[i] = *(const bf16x8*)(&As[(wr * 64 + i * 16 + (lane & 15)) * LDK + kidx]);
#pragma unroll
            for (int j = 0; j < 4; ++j)
                bfv[j] = *(const bf16x8*)(&Bs[(wc * 64 + j * 16 + (lane & 15)) * LDK + kidx]);
#pragma unroll
            for (int i = 0; i < 4; ++i)
#pragma unroll
                for (int j = 0; j < 4; ++j)
                    acc[i][j] = __builtin_amdgcn_mfma_f32_16x16x32_bf16(afv[i], bfv[j], acc[i][j], 0, 0, 0);
        }
    }

    const int orow_base = m0 + wr * 64 + ((lane >> 4) << 2);
    const int ocol_base = n0 + wc * 64 + (lane & 15);
#pragma unroll
    for (int j = 0; j < 4; ++j) {
        const float bv = bias[ocol_base + j * 16];
#pragma unroll
        for (int i = 0; i < 4; ++i) {
#pragma unroll
            for (int q = 0; q < 4; ++q) {
                out[(size_t)(orow_base + i * 16 + q) * OUT_F + (ocol_base + j * 16)] =
                    acc[i][j][q] + bv;
            }
        }
    }
}

// ---------------------------------------------------------------------------
extern "C" void kernel_launch(void* const* d_in, const int* in_sizes, int n_in,
                              void* d_out, int out_size, void* d_ws, size_t ws_size,
                              hipStream_t stream) {
    const float* x      = (const float*)d_in[0];
    const int*   qw     = (const int*)d_in[1];
    const float* scales = (const float*)d_in[2];
    const float* zeros  = (const float*)d_in[3];
    const float* bias   = (const float*)d_in[4];
    float* out = (float*)d_out;

    const size_t wt_bytes = (size_t)OUT_F * IN_F * sizeof(unsigned short);   // 90.2 MB
    const size_t xb_bytes = (size_t)M_TOTAL * IN_F * sizeof(unsigned short); // 67.1 MB

    if (ws_size >= wt_bytes + xb_bytes) {
        unsigned short* wt = (unsigned short*)d_ws;
        unsigned short* xb = (unsigned short*)((char*)d_ws + wt_bytes);
        convert_x_kernel<<<(M_TOTAL * IN_F) / (256 * 8), 256, 0, stream>>>(x, xb);
        dequant_w_kernel<<<dim3(OUT_F / 256, IN_F / 32), 256, 0, stream>>>(qw, scales, zeros, wt);
        gemm_8phase<<<(M_TOTAL / 256) * (OUT_F / 256), 512, 0, stream>>>(xb, wt, bias, out);
    } else if (ws_size >= wt_bytes) {
        unsigned short* wt = (unsigned short*)d_ws;
        dequant_w_kernel<<<dim3(OUT_F / 256, IN_F / 32), 256, 0, stream>>>(qw, scales, zeros, wt);
        gemm_kernel<true><<<(M_TOTAL / 128) * (OUT_F / 128), 256, 0, stream>>>(x, wt, qw, scales, zeros, bias, out);
    } else {
        gemm_kernel<false><<<(M_TOTAL / 128) * (OUT_F / 128), 256, 0, stream>>>(x, nullptr, qw, scales, zeros, bias, out);
    }
}

// Round 6
// 869.230 us; speedup vs baseline: 1.5784x; 1.0040x over previous
//
#include <hip/hip_runtime.h>
#include <hip/hip_bf16.h>

#define IN_F 4096
#define OUT_F 11008
#define GSIZE 128
#define M_TOTAL 8192

typedef float f32x4 __attribute__((ext_vector_type(4)));
typedef unsigned short u16x8 __attribute__((ext_vector_type(8)));
typedef unsigned int u32x4 __attribute__((ext_vector_type(4)));
typedef __bf16 bf16x8 __attribute__((ext_vector_type(8)));

#define ASG __attribute__((address_space(1)))
#define ASL __attribute__((address_space(3)))

__device__ __forceinline__ unsigned short f2bf(float f) {
    union { float f; unsigned int u; } v;
    v.f = f;
    unsigned int u = v.u;
    unsigned int r = (u + 0x7fffu + ((u >> 16) & 1u)) >> 16;
    return (unsigned short)r;
}

// ---------------------------------------------------------------------------
// Pass 0: convert x fp32 -> bf16 [M][K] in ws.
// ---------------------------------------------------------------------------
__global__ void convert_x_kernel(const float* __restrict__ x,
                                 unsigned short* __restrict__ xb) {
    const size_t i = ((size_t)blockIdx.x * 256 + threadIdx.x) * 8;
    f32x4 a = *(const f32x4*)(x + i);
    f32x4 b = *(const f32x4*)(x + i + 4);
    u16x8 v;
#pragma unroll
    for (int e = 0; e < 4; ++e) {
        v[e]     = f2bf(a[e]);
        v[e + 4] = f2bf(b[e]);
    }
    *(u16x8*)(xb + i) = v;
}

// ---------------------------------------------------------------------------
// Pass 1: dequantize packed int4 weights -> W^T bf16 [OUT_F][IN_F] in ws.
// ---------------------------------------------------------------------------
__global__ void dequant_w_kernel(const int* __restrict__ qw,
                                 const float* __restrict__ scales,
                                 const float* __restrict__ zeros,
                                 unsigned short* __restrict__ wt) {
    const int n  = blockIdx.x * 256 + threadIdx.x;
    const int k0 = blockIdx.y * 32;
    const int g  = k0 >> 7;
    const float s = scales[(size_t)g * OUT_F + n];
    const float z = zeros[(size_t)g * OUT_F + n];

    unsigned short outv[32];
#pragma unroll
    for (int i = 0; i < 16; ++i) {
        int q = qw[(size_t)(k0 / 2 + i) * OUT_F + n];
        float lo = (float)((q & 15) - 8) * s + z;        // even k = low nibble
        float hi = (float)(((q >> 4) & 15) - 8) * s + z; // odd k  = high nibble
        outv[2 * i]     = f2bf(lo);
        outv[2 * i + 1] = f2bf(hi);
    }
    u16x8* dst = (u16x8*)(wt + (size_t)n * IN_F + k0);
    const u16x8* src = (const u16x8*)outv;
#pragma unroll
    for (int i = 0; i < 4; ++i) dst[i] = src[i];
}

// ---------------------------------------------------------------------------
// Pass 2: 256x256 bf16 GEMM, 4-barrier-per-K-tile zoned schedule.
// Zones (between fenced barriers), tile t buf p:
//  Z0 = [QUAD11(prev) ; READ_A0(p)->afH0, READ_BLO(p)->bf01 ; stage A1(t+1)->!p]
//  Z1 = [QUAD00       ; READ_BHI(p)->bf23                   ; stage B-G0(t+2)->p]
//  Z2 = [QUAD01       ; READ_A1(p)->afH1                    ; stage B-G1(t+2)->p]
//  Z3 = [QUAD10       ;                                      stage A0(t+2)->p ; vmcnt(6)]
// Register-WAR-free inside every zone (QUAD's operand arrays disjoint from the
// zone's read-destination arrays) -> compiler may interleave reads/stages under
// the MFMA cluster. sched_barrier(0) fences at every s_barrier stop any motion
// across barriers (round-4 NaN mechanism).
// WAR (LDS): A1->!p: A-H1(!p) last read t-1.Z2 (2 bars). B-G0->p: G0 frags
// last read t.Z0 (1 bar). B-G1->p: last read t.Z1 (1 bar). A0->p: last read
// t.Z0 (2 bars). B staging grouped by FRAGMENT-GROUP (G0={0,1,4,5,8,9,12,13},
// G1=+2) so group == reader set for every wave.
// RAW: vmcnt(6) at t.Z3 retires the 8 oldest of 14 in-flight stage insts =
// all of tile t+1; barrier follows before Z0 reads it.
// ---------------------------------------------------------------------------
__global__ __launch_bounds__(512, 1)
void gemm_8phase(const unsigned short* __restrict__ xb,   // [M][K] bf16
                 const unsigned short* __restrict__ wt,   // [N][K] bf16
                 const float* __restrict__ bias,
                 float* __restrict__ out) {
    constexpr int NT = IN_F / 64;  // 64 K-tiles
    __shared__ __attribute__((aligned(128))) unsigned short lds[65536]; // 128 KiB

    constexpr int NB_N = OUT_F / 256;             // 43
    constexpr int NWG  = (M_TOTAL / 256) * NB_N;  // 1376 (divisible by 8)
    constexpr int CPX  = NWG / 8;                 // 172
    const int wg = ((int)blockIdx.x % 8) * CPX + (int)blockIdx.x / 8;
    const int m0 = (wg / NB_N) * 256;
    const int n0 = (wg % NB_N) * 256;

    const int tid  = threadIdx.x;
    const int lane = tid & 63;
    const int wave = tid >> 6;       // 0..7
    const int wr = wave >> 2;        // 0..1  (M)
    const int wc = wave & 3;         // 0..3  (N)
    const int r16 = lane & 15;
    const int q4  = lane >> 4;

    const ASG char* xbc = (const ASG char*)xb;
    const ASG char* wtc = (const ASG char*)wt;
    ASL char* ldsc = (ASL char*)lds;

    // ---- staging streams (per-thread 32-bit global byte offsets, advanced
    // +128 B per use; wave-uniform LDS dest byte offsets).
    // A streams H*2+i: subtile s=i*8+wave -> frag f=s>>1 (global fa=H*8+f), kc=s&1.
    // B group streams G*2+i: s=i*8+wave -> fg=(s>>2)*4+G*2+((s>>1)&1), kc=s&1.
    unsigned int oA[4], oBG[4];
    int dA[4], dBG[4];
#pragma unroll
    for (int H = 0; H < 2; ++H)
#pragma unroll
        for (int i = 0; i < 2; ++i) {
            const int s = i * 8 + wave;
            const int f = s >> 1, kc = s & 1;
            oA[H * 2 + i] = (unsigned int)(((m0 + H * 128 + f * 16 + r16) * IN_F +
                                            kc * 32 + q4 * 8) * 2);
            dA[H * 2 + i] = ((H * 8 + f) * 2 + kc) * 1024;
        }
#pragma unroll
    for (int G = 0; G < 2; ++G)
#pragma unroll
        for (int i = 0; i < 2; ++i) {
            const int s = i * 8 + wave;
            const int fg = (s >> 2) * 4 + G * 2 + ((s >> 1) & 1);
            const int kc = s & 1;
            oBG[G * 2 + i] = (unsigned int)(((n0 + fg * 16 + r16) * IN_F +
                                             kc * 32 + q4 * 8) * 2);
            dBG[G * 2 + i] = 32768 + (fg * 2 + kc) * 1024;
        }

#define STG_A(H, P)                                                            \
    do {                                                                       \
        _Pragma("unroll") for (int _i = 0; _i < 2; ++_i)                       \
            __builtin_amdgcn_global_load_lds(                                  \
                (ASG const unsigned int*)(xbc + oA[(H) * 2 + _i]),             \
                (ASL unsigned int*)(ldsc + dA[(H) * 2 + _i] + (P) * 65536),    \
                16, 0, 0);                                                     \
    } while (0)
#define STG_BG(G, P)                                                           \
    do {                                                                       \
        _Pragma("unroll") for (int _i = 0; _i < 2; ++_i)                       \
            __builtin_amdgcn_global_load_lds(                                  \
                (ASG const unsigned int*)(wtc + oBG[(G) * 2 + _i]),            \
                (ASL unsigned int*)(ldsc + dBG[(G) * 2 + _i] + (P) * 65536),   \
                16, 0, 0);                                                     \
    } while (0)
#define ADV_A(H) do { oA[(H)*2] += 128; oA[(H)*2+1] += 128; } while (0)
#define ADV_BG(G) do { oBG[(G)*2] += 128; oBG[(G)*2+1] += 128; } while (0)

// hard region boundary: nothing schedules across the barrier
#define BAR()                                                                  \
    do {                                                                       \
        __builtin_amdgcn_sched_barrier(0);                                     \
        __builtin_amdgcn_s_barrier();                                          \
        __builtin_amdgcn_sched_barrier(0);                                     \
    } while (0)

    // split fragment arrays -> zero register WAR inside any zone
    bf16x8 afH0[4][2], afH1[4][2];   // M-half 0 / 1: 4 frags x 2 k-chunks
    bf16x8 bf01[2][2], bf23[2][2];   // B frag-groups lo/hi x 2 k-chunks
    f32x4  acc[8][4];
#pragma unroll
    for (int i = 0; i < 8; ++i)
#pragma unroll
        for (int j = 0; j < 4; ++j) acc[i][j] = (f32x4)0.0f;

#define READ_A0(P)                                                             \
    do {                                                                       \
        const unsigned short* _ab = lds + (P) * 32768 + lane * 8;              \
        _Pragma("unroll") for (int _ii = 0; _ii < 4; ++_ii)                    \
        _Pragma("unroll") for (int _kc = 0; _kc < 2; ++_kc)                    \
            afH0[_ii][_kc] = *(const bf16x8*)(_ab +                            \
                (((wr * 8 + _ii) * 2 + _kc) << 9));                            \
    } while (0)
#define READ_A1(P)                                                             \
    do {                                                                       \
        const unsigned short* _ab = lds + (P) * 32768 + lane * 8;              \
        _Pragma("unroll") for (int _ii = 0; _ii < 4; ++_ii)                    \
        _Pragma("unroll") for (int _kc = 0; _kc < 2; ++_kc)                    \
            afH1[_ii][_kc] = *(const bf16x8*)(_ab +                            \
                (((wr * 8 + 4 + _ii) * 2 + _kc) << 9));                        \
    } while (0)
#define READ_BLO(P)                                                            \
    do {                                                                       \
        const unsigned short* _bb = lds + (P) * 32768 + 16384 + lane * 8;      \
        _Pragma("unroll") for (int _g = 0; _g < 2; ++_g)                       \
        _Pragma("unroll") for (int _kc = 0; _kc < 2; ++_kc)                    \
            bf01[_g][_kc] = *(const bf16x8*)(_bb +                             \
                (((wc * 4 + _g) * 2 + _kc) << 9));                             \
    } while (0)
#define READ_BHI(P)                                                            \
    do {                                                                       \
        const unsigned short* _bb = lds + (P) * 32768 + 16384 + lane * 8;      \
        _Pragma("unroll") for (int _g = 0; _g < 2; ++_g)                       \
        _Pragma("unroll") for (int _kc = 0; _kc < 2; ++_kc)                    \
            bf23[_g][_kc] = *(const bf16x8*)(_bb +                             \
                (((wc * 4 + 2 + _g) * 2 + _kc) << 9));                         \
    } while (0)

#define QUADX(AF, BF, MH, NH)                                                  \
    do {                                                                       \
        __builtin_amdgcn_s_setprio(1);                                         \
        _Pragma("unroll") for (int _ii = 0; _ii < 4; ++_ii)                    \
        _Pragma("unroll") for (int _g = 0; _g < 2; ++_g)                       \
        _Pragma("unroll") for (int _kc = 0; _kc < 2; ++_kc)                    \
            acc[(MH) * 4 + _ii][(NH) * 2 + _g] =                               \
                __builtin_amdgcn_mfma_f32_16x16x32_bf16(                       \
                    AF[_ii][_kc], BF[_g][_kc],                                 \
                    acc[(MH) * 4 + _ii][(NH) * 2 + _g], 0, 0, 0);              \
        __builtin_amdgcn_s_setprio(0);                                         \
    } while (0)

    // ---- prologue: tile0 {BG0,BG1,A0,A1}, tile1 {BG0,BG1,A0}; 6 in flight.
    STG_BG(0, 0); ADV_BG(0);
    STG_BG(1, 0); ADV_BG(1);
    STG_A(0, 0);  ADV_A(0);
    STG_A(1, 0);  ADV_A(1);    // A1 stream -> T=1
    STG_BG(0, 1); ADV_BG(0);   // -> T=2
    STG_BG(1, 1); ADV_BG(1);   // -> T=2
    STG_A(0, 1);  ADV_A(0);    // -> T=2
    __builtin_amdgcn_sched_barrier(0);
    asm volatile("s_waitcnt vmcnt(6)" ::: "memory");  // tile0 resident
    BAR();

#pragma unroll 1
    for (int tt = 0; tt < NT; tt += 2) {
        const bool g2 = (tt + 2 < NT);
        const bool g3 = (tt + 3 < NT);
        // ================= tile tt (buf 0) =================
        // Z0 (continues prev iter's QUAD11)
        READ_A0(0);
        READ_BLO(0);
        STG_A(1, 1); ADV_A(1);                // A1(tt+1) -> buf1
        BAR();
        // Z1
        QUADX(afH0, bf01, 0, 0);
        READ_BHI(0);
        if (g2) STG_BG(0, 0);
        ADV_BG(0);                            // B-G0(tt+2) -> buf0
        BAR();
        // Z2
        QUADX(afH0, bf23, 0, 1);
        READ_A1(0);
        if (g2) STG_BG(1, 0);
        ADV_BG(1);                            // B-G1(tt+2) -> buf0
        BAR();
        // Z3
        QUADX(afH1, bf01, 1, 0);
        if (g2) STG_A(0, 0);
        ADV_A(0);                             // A0(tt+2) -> buf0
        __builtin_amdgcn_sched_barrier(0);
        if (tt < NT - 2) {
            asm volatile("s_waitcnt vmcnt(6)" ::: "memory");
        } else {
            asm volatile("s_waitcnt vmcnt(0)" ::: "memory");
        }
        BAR();
        QUADX(afH1, bf23, 1, 1);
        // ================= tile tt+1 (buf 1) =================
        // Z0 (same zone as QUAD11 above)
        READ_A0(1);
        READ_BLO(1);
        if (g2) STG_A(1, 0);
        ADV_A(1);                             // A1(tt+2) -> buf0
        BAR();
        // Z1
        QUADX(afH0, bf01, 0, 0);
        READ_BHI(1);
        if (g3) STG_BG(0, 1);
        ADV_BG(0);                            // B-G0(tt+3) -> buf1
        BAR();
        // Z2
        QUADX(afH0, bf23, 0, 1);
        READ_A1(1);
        if (g3) STG_BG(1, 1);
        ADV_BG(1);                            // B-G1(tt+3) -> buf1
        BAR();
        // Z3
        QUADX(afH1, bf01, 1, 0);
        if (g3) STG_A(0, 1);
        ADV_A(0);                             // A0(tt+3) -> buf1
        __builtin_amdgcn_sched_barrier(0);
        if (tt + 1 < NT - 2) {
            asm volatile("s_waitcnt vmcnt(6)" ::: "memory");
        } else {
            asm volatile("s_waitcnt vmcnt(0)" ::: "memory");
        }
        BAR();
        QUADX(afH1, bf23, 1, 1);
    }

    // ---- epilogue: C/D col = lane&15, row = (lane>>4)*4 + q
#pragma unroll
    for (int g = 0; g < 4; ++g) {
        const int col = n0 + wc * 64 + g * 16 + r16;
        const float bv = bias[col];
#pragma unroll
        for (int fl = 0; fl < 8; ++fl) {
            const int row0 = m0 + wr * 128 + fl * 16 + q4 * 4;
#pragma unroll
            for (int qq = 0; qq < 4; ++qq)
                out[(size_t)(row0 + qq) * OUT_F + col] = acc[fl][g][qq] + bv;
        }
    }
#undef STG_A
#undef STG_BG
#undef ADV_A
#undef ADV_BG
#undef BAR
#undef READ_A0
#undef READ_A1
#undef READ_BLO
#undef READ_BHI
#undef QUADX
}

// ---------------------------------------------------------------------------
// Fallback GEMM (reg-staged 128x128), for small ws.
// ---------------------------------------------------------------------------
template <bool PREW>
__global__ __launch_bounds__(256, 2)
void gemm_kernel(const float* __restrict__ x,
                 const unsigned short* __restrict__ wt,
                 const int* __restrict__ qw,
                 const float* __restrict__ scales,
                 const float* __restrict__ zeros,
                 const float* __restrict__ bias,
                 float* __restrict__ out) {
    constexpr int BM = 128, BN = 128, BK = 64;
    constexpr int LDK = BK + 8;
    constexpr int NT = IN_F / BK;

    __shared__ unsigned short As[BM * LDK];
    __shared__ unsigned short Bs[BN * LDK];

    const int bid = blockIdx.x;
    constexpr int NB_N = OUT_F / BN;
    const int m0 = (bid / NB_N) * BM;
    const int n0 = (bid % NB_N) * BN;

    const int tid  = threadIdx.x;
    const int lane = tid & 63;
    const int wave = tid >> 6;
    const int wr = wave >> 1, wc = wave & 1;

    const int st_row = tid >> 3;
    const int st_col = (tid & 7) * 8;

    f32x4 areg[4][2];
    u32x4 breg[4];
    int   qreg[16];
    float s_, z_;
    const int b_n  = tid & 127;
    const int b_kp = (tid >> 7) * 16;

    auto load_tile = [&](int kt) {
        {
            const float* base = x + (size_t)m0 * IN_F + (size_t)kt * BK + st_col;
#pragma unroll
            for (int p = 0; p < 4; ++p) {
                const float* rp = base + (size_t)(p * 32 + st_row) * IN_F;
                areg[p][0] = *(const f32x4*)rp;
                areg[p][1] = *(const f32x4*)(rp + 4);
            }
        }
        if constexpr (PREW) {
            const unsigned short* base = wt + (size_t)n0 * IN_F + (size_t)kt * BK + st_col;
#pragma unroll
            for (int p = 0; p < 4; ++p)
                breg[p] = *(const u32x4*)(base + (size_t)(p * 32 + st_row) * IN_F);
        } else {
            const int kp0 = kt * (BK / 2) + b_kp;
#pragma unroll
            for (int i = 0; i < 16; ++i)
                qreg[i] = qw[(size_t)(kp0 + i) * OUT_F + n0 + b_n];
            const int g = (kt * BK) >> 7;
            s_ = scales[(size_t)g * OUT_F + n0 + b_n];
            z_ = zeros[(size_t)g * OUT_F + n0 + b_n];
        }
    };

    auto write_lds = [&]() {
#pragma unroll
        for (int p = 0; p < 4; ++p) {
            u16x8 v;
#pragma unroll
            for (int e = 0; e < 4; ++e) {
                v[e]     = f2bf(areg[p][0][e]);
                v[e + 4] = f2bf(areg[p][1][e]);
            }
            *(u16x8*)(&As[(p * 32 + st_row) * LDK + st_col]) = v;
        }
        if constexpr (PREW) {
#pragma unroll
            for (int p = 0; p < 4; ++p)
                *(u32x4*)(&Bs[(p * 32 + st_row) * LDK + st_col]) = breg[p];
        } else {
            unsigned short tmp[32];
#pragma unroll
            for (int i = 0; i < 16; ++i) {
                int q = qreg[i];
                tmp[2 * i]     = f2bf((float)((q & 15) - 8) * s_ + z_);
                tmp[2 * i + 1] = f2bf((float)(((q >> 4) & 15) - 8) * s_ + z_);
            }
            const u16x8* srcv = (const u16x8*)tmp;
#pragma unroll
            for (int i = 0; i < 4; ++i)
                *(u16x8*)(&Bs[b_n * LDK + 2 * b_kp + 8 * i]) = srcv[i];
        }
    };

    f32x4 acc[4][4];
#pragma unroll
    for (int i = 0; i < 4; ++i)
#pragma unroll
        for (int j = 0; j < 4; ++j) acc[i][j] = (f32x4)0.0f;

    load_tile(0);

#pragma unroll 1
    for (int kt = 0; kt < NT; ++kt) {
        __syncthreads();
        write_lds();
        __syncthreads();
        if (kt + 1 < NT) load_tile(kt + 1);

#pragma unroll
        for (int kk = 0; kk < 2; ++kk) {
            const int kidx = kk * 32 + ((lane >> 4) << 3);
            bf16x8 afv[4], bfv[4];
#pragma unroll
            for (int i = 0; i < 4; ++i)
                afv[i] = *(const bf16x8*)(&As[(wr * 64 + i * 16 + (lane & 15)) * LDK + kidx]);
#pragma unroll
            for (int j = 0; j < 4; ++j)
                bfv[j] = *(const bf16x8*)(&Bs[(wc * 64 + j * 16 + (lane & 15)) * LDK + kidx]);
#pragma unroll
            for (int i = 0; i < 4; ++i)
#pragma unroll
                for (int j = 0; j < 4; ++j)
                    acc[i][j] = __builtin_amdgcn_mfma_f32_16x16x32_bf16(afv[i], bfv[j], acc[i][j], 0, 0, 0);
        }
    }

    const int orow_base = m0 + wr * 64 + ((lane >> 4) << 2);
    const int ocol_base = n0 + wc * 64 + (lane & 15);
#pragma unroll
    for (int j = 0; j < 4; ++j) {
        const float bv = bias[ocol_base + j * 16];
#pragma unroll
        for (int i = 0; i < 4; ++i) {
#pragma unroll
            for (int q = 0; q < 4; ++q) {
                out[(size_t)(orow_base + i * 16 + q) * OUT_F + (ocol_base + j * 16)] =
                    acc[i][j][q] + bv;
            }
        }
    }
}

// ---------------------------------------------------------------------------
extern "C" void kernel_launch(void* const* d_in, const int* in_sizes, int n_in,
                              void* d_out, int out_size, void* d_ws, size_t ws_size,
                              hipStream_t stream) {
    const float* x      = (const float*)d_in[0];
    const int*   qw     = (const int*)d_in[1];
    const float* scales = (const float*)d_in[2];
    const float* zeros  = (const float*)d_in[3];
    const float* bias   = (const float*)d_in[4];
    float* out = (float*)d_out;

    const size_t wt_bytes = (size_t)OUT_F * IN_F * sizeof(unsigned short);   // 90.2 MB
    const size_t xb_bytes = (size_t)M_TOTAL * IN_F * sizeof(unsigned short); // 67.1 MB

    if (ws_size >= wt_bytes + xb_bytes) {
        unsigned short* wt = (unsigned short*)d_ws;
        unsigned short* xb = (unsigned short*)((char*)d_ws + wt_bytes);
        convert_x_kernel<<<(M_TOTAL * IN_F) / (256 * 8), 256, 0, stream>>>(x, xb);
        dequant_w_kernel<<<dim3(OUT_F / 256, IN_F / 32), 256, 0, stream>>>(qw, scales, zeros, wt);
        gemm_8phase<<<(M_TOTAL / 256) * (OUT_F / 256), 512, 0, stream>>>(xb, wt, bias, out);
    } else if (ws_size >= wt_bytes) {
        unsigned short* wt = (unsigned short*)d_ws;
        dequant_w_kernel<<<dim3(OUT_F / 256, IN_F / 32), 256, 0, stream>>>(qw, scales, zeros, wt);
        gemm_kernel<true><<<(M_TOTAL / 128) * (OUT_F / 128), 256, 0, stream>>>(x, wt, qw, scales, zeros, bias, out);
    } else {
        gemm_kernel<false><<<(M_TOTAL / 128) * (OUT_F / 128), 256, 0, stream>>>(x, nullptr, qw, scales, zeros, bias, out);
    }
}